// Round 1
// baseline (1767.371 us; speedup 1.0000x reference)
//
#include <hip/hip_runtime.h>
#include <hip/hip_bf16.h>

// GCN 2-layer: z = A_n(relu(A_n(x@W1)+b1)@W2)+b2, A_n = D^-1/2 (A+I) D^-1/2
// N=100000, E=1600000, IN=768, HID=128, OUT=64. All fp32.

static constexpr int NN   = 100000;
static constexpr int NE   = 1600000;
static constexpr int C_IN  = 768;
static constexpr int C_HID = 128;
static constexpr int C_OUT = 64;

__global__ void k_fill(float* __restrict__ p, float v, int n) {
    int i = blockIdx.x * blockDim.x + threadIdx.x;
    if (i < n) p[i] = v;
}

__global__ void k_count(const int* __restrict__ dst, float* __restrict__ deg, int e) {
    int stride = gridDim.x * blockDim.x;
    for (int i = blockIdx.x * blockDim.x + threadIdx.x; i < e; i += stride)
        unsafeAtomicAdd(&deg[dst[i]], 1.0f);
}

__global__ void k_rsqrt_inplace(float* __restrict__ deg, int n) {
    int i = blockIdx.x * blockDim.x + threadIdx.x;
    if (i < n) deg[i] = rsqrtf(deg[i]);   // deg >= 1 always (self-loop), no zero case
}

// C[M,N] = A[M,K] @ B[K,N]; tile 64xN per block, BK=32, 256 threads.
// Threads: 16x16; each thread 4 rows x (N/16) cols.
template<int K, int N>
__global__ __launch_bounds__(256) void k_gemm(const float* __restrict__ A,
                                              const float* __restrict__ B,
                                              float* __restrict__ C, int M) {
    constexpr int BM = 64, BK = 32;
    constexpr int CPT = N / 16;          // 8 (N=128) or 4 (N=64)
    __shared__ float sA[BK][BM + 4];     // transposed A tile; +4 keeps 16B alignment
    __shared__ float sB[BK][N];

    const int tid  = threadIdx.x;
    const int row0 = blockIdx.x * BM;
    const int tr   = tid >> 4;           // 0..15 -> rows tr*4 .. tr*4+3
    const int tc   = tid & 15;           // 0..15 -> cols tc*CPT ..

    float acc[4][CPT];
    #pragma unroll
    for (int i = 0; i < 4; ++i)
        #pragma unroll
        for (int j = 0; j < CPT; ++j) acc[i][j] = 0.f;

    for (int k0 = 0; k0 < K; k0 += BK) {
        // Load A tile: 64 rows x 32 k (512 float4, 2 per thread), store transposed.
        #pragma unroll
        for (int l = 0; l < 2; ++l) {
            int t  = tid + l * 256;       // 0..511
            int r  = t >> 3;              // 0..63
            int cc = (t & 7) << 2;        // 0,4,...,28
            int gr = row0 + r;
            float4 v = make_float4(0.f, 0.f, 0.f, 0.f);
            if (gr < M) v = *(const float4*)(A + (long long)gr * K + k0 + cc);
            sA[cc + 0][r] = v.x; sA[cc + 1][r] = v.y;
            sA[cc + 2][r] = v.z; sA[cc + 3][r] = v.w;
        }
        // Load B tile: 32 rows x N cols.
        #pragma unroll
        for (int l = 0; l < (8 * N) / 256; ++l) {
            int t  = tid + l * 256;
            int r  = t / (N / 4);
            int cc = (t % (N / 4)) << 2;
            *(float4*)(&sB[r][cc]) = *(const float4*)(B + (long long)(k0 + r) * N + cc);
        }
        __syncthreads();
        #pragma unroll
        for (int k = 0; k < BK; ++k) {
            float a[4], b[CPT];
            *(float4*)a = *(const float4*)(&sA[k][tr * 4]);
            #pragma unroll
            for (int j = 0; j < CPT; j += 4)
                *(float4*)(&b[j]) = *(const float4*)(&sB[k][tc * CPT + j]);
            #pragma unroll
            for (int i = 0; i < 4; ++i)
                #pragma unroll
                for (int j = 0; j < CPT; ++j)
                    acc[i][j] += a[i] * b[j];
        }
        __syncthreads();
    }
    #pragma unroll
    for (int i = 0; i < 4; ++i) {
        int row = row0 + tr * 4 + i;
        if (row < M) {
            #pragma unroll
            for (int j = 0; j < CPT; j += 4)
                *(float4*)(C + (long long)row * N + tc * CPT + j) = *(float4*)(&acc[i][j]);
        }
    }
}

// feat[n,c] *= dis[n]  (pre-scale by dis[src] for edge msgs), and
// init[n,c] = feat_scaled * dis[n] + bias[c]   (self-loop term + bias, added once)
__global__ void k_scale_init(float* __restrict__ feat, const float* __restrict__ dis,
                             float* __restrict__ init, const float* __restrict__ bias,
                             int total, int logc) {
    int mask = (1 << logc) - 1;
    int stride = gridDim.x * blockDim.x;
    for (int i = blockIdx.x * blockDim.x + threadIdx.x; i < total; i += stride) {
        int node = i >> logc;
        float dn = dis[node];
        float f = feat[i] * dn;
        feat[i] = f;
        init[i] = f * dn + bias[i & mask];
    }
}

// out[dst,c] += feat_scaled[src,c] * dis[dst]   (feat already scaled by dis[src])
__global__ void k_edge(const int* __restrict__ src, const int* __restrict__ dst,
                       const float* __restrict__ dis, const float* __restrict__ feat,
                       float* __restrict__ out, int total, int logc) {
    int mask = (1 << logc) - 1;
    int stride = gridDim.x * blockDim.x;
    for (int i = blockIdx.x * blockDim.x + threadIdx.x; i < total; i += stride) {
        int e = i >> logc, c = i & mask;
        int s = src[e], d = dst[e];
        float v = feat[((long long)s << logc) + c] * dis[d];
        unsafeAtomicAdd(&out[((long long)d << logc) + c], v);
    }
}

__global__ void k_relu(float* __restrict__ p, int n) {
    int stride = gridDim.x * blockDim.x;
    for (int i = blockIdx.x * blockDim.x + threadIdx.x; i < n; i += stride)
        p[i] = fmaxf(p[i], 0.f);
}

extern "C" void kernel_launch(void* const* d_in, const int* in_sizes, int n_in,
                              void* d_out, int out_size, void* d_ws, size_t ws_size,
                              hipStream_t stream) {
    const float* x  = (const float*)d_in[0];
    const int*   ei = (const int*)d_in[1];
    const float* W1 = (const float*)d_in[2];
    const float* b1 = (const float*)d_in[3];
    const float* W2 = (const float*)d_in[4];
    const float* b2 = (const float*)d_in[5];
    float* z = (float*)d_out;

    char* ws  = (char*)d_ws;
    float* deg = (float*)ws;                          // 100000 floats (becomes dis)
    float* xw  = (float*)(ws + (1 << 19));            // 51.2 MB, reused as hw later
    float* h   = (float*)(ws + (1 << 19) + 51200000); // 51.2 MB

    const int* src = ei;
    const int* dst = ei + NE;

    // degree + symmetric norm (deg includes self-loop)
    k_fill<<<(NN + 255) / 256, 256, 0, stream>>>(deg, 1.0f, NN);
    k_count<<<4096, 256, 0, stream>>>(dst, deg, NE);
    k_rsqrt_inplace<<<(NN + 255) / 256, 256, 0, stream>>>(deg, NN);

    // layer 1
    k_gemm<C_IN, C_HID><<<(NN + 63) / 64, 256, 0, stream>>>(x, W1, xw, NN);
    k_scale_init<<<8192, 256, 0, stream>>>(xw, deg, h, b1, NN * C_HID, 7);
    k_edge<<<16384, 256, 0, stream>>>(src, dst, deg, xw, h, NE * C_HID, 7);
    k_relu<<<8192, 256, 0, stream>>>(h, NN * C_HID);

    // layer 2 (hw reuses xw buffer)
    float* hw = xw;
    k_gemm<C_HID, C_OUT><<<(NN + 63) / 64, 256, 0, stream>>>(h, W2, hw, NN);
    k_scale_init<<<8192, 256, 0, stream>>>(hw, deg, z, b2, NN * C_OUT, 6);
    k_edge<<<16384, 256, 0, stream>>>(src, dst, deg, hw, z, NE * C_OUT, 6);
}

// Round 7
// 990.549 us; speedup vs baseline: 1.7842x; 1.7842x over previous
//
#include <hip/hip_runtime.h>
#include <hip/hip_bf16.h>

// GCN 2-layer: z = A_n(relu(A_n(x@W1)+b1)@W2)+b2, A_n = D^-1/2 (A+I) D^-1/2
// N=100000, E=1600000, IN=768, HID=128, OUT=64. All fp32.
// R2..R7: CSR-by-dst built on device each call; gather-sum aggregation (no
// float atomics); dis-scale fused into GEMM epilogue; bias+self+relu in agg.

static constexpr int NN    = 100000;
static constexpr int NE    = 1600000;
static constexpr int C_IN  = 768;
static constexpr int C_HID = 128;
static constexpr int C_OUT = 64;
static constexpr int SCAN_B = 256;
static constexpr int NB_SCAN = (NN + SCAN_B - 1) / SCAN_B;   // 391

__global__ void k_zero_i(int* __restrict__ p, int n) {
    int i = blockIdx.x * blockDim.x + threadIdx.x;
    if (i < n) p[i] = 0;
}

__global__ void k_hist(const int* __restrict__ dst, int* __restrict__ cnt, int e) {
    int stride = gridDim.x * blockDim.x;
    for (int i = blockIdx.x * blockDim.x + threadIdx.x; i < e; i += stride)
        atomicAdd(&cnt[dst[i]], 1);
}

__global__ void k_dis(const int* __restrict__ cnt, float* __restrict__ dis, int n) {
    int i = blockIdx.x * blockDim.x + threadIdx.x;
    if (i < n) dis[i] = rsqrtf((float)cnt[i] + 1.0f);   // +1 self-loop, never 0
}

// per-block inclusive scan of cnt -> rp1[i] (= rowptr+1), block sums -> bsum
__global__ __launch_bounds__(SCAN_B) void k_scan1(const int* __restrict__ cnt,
                                                  int* __restrict__ rp1,
                                                  int* __restrict__ bsum, int n) {
    __shared__ int sh[SCAN_B];
    int b = blockIdx.x, t = threadIdx.x, i = b * SCAN_B + t;
    sh[t] = (i < n) ? cnt[i] : 0;
    __syncthreads();
    for (int off = 1; off < SCAN_B; off <<= 1) {
        int u = (t >= off) ? sh[t - off] : 0;
        __syncthreads();
        sh[t] += u;
        __syncthreads();
    }
    if (i < n) rp1[i] = sh[t];
    if (t == SCAN_B - 1) bsum[b] = sh[t];
}

// single-block inclusive scan of bsum[nb]
__global__ __launch_bounds__(512) void k_scan2(int* __restrict__ bsum, int nb) {
    __shared__ int sh[512];
    int t = threadIdx.x;
    sh[t] = (t < nb) ? bsum[t] : 0;
    __syncthreads();
    for (int off = 1; off < 512; off <<= 1) {
        int u = (t >= off) ? sh[t - off] : 0;
        __syncthreads();
        sh[t] += u;
        __syncthreads();
    }
    if (t < nb) bsum[t] = sh[t];
}

// rowptr[1+i] += bsum[b-1]; rowptr[0] = 0; cursor[i] = final rowptr[i]
__global__ __launch_bounds__(SCAN_B) void k_scan3(int* __restrict__ rowptr,
                                                  const int* __restrict__ bsum,
                                                  int* __restrict__ cursor, int n) {
    int b = blockIdx.x, t = threadIdx.x, i = b * SCAN_B + t;
    if (b == 0 && t == 0) { rowptr[0] = 0; cursor[0] = 0; }
    if (i < n) {
        int v = rowptr[1 + i] + (b > 0 ? bsum[b - 1] : 0);
        rowptr[1 + i] = v;
        if (i + 1 < n) cursor[i + 1] = v;   // cursor[d] = exclusive start of row d
    }
}

__global__ void k_scatter(const int* __restrict__ src, const int* __restrict__ dst,
                          int* __restrict__ cursor, int* __restrict__ csr, int e) {
    int stride = gridDim.x * blockDim.x;
    for (int i = blockIdx.x * blockDim.x + threadIdx.x; i < e; i += stride) {
        int p = atomicAdd(&cursor[dst[i]], 1);
        csr[p] = src[i];
    }
}

// C[M,N] = (A[M,K] @ B[K,N]) * dis[row]; tile 64xN, BK=32, 256 threads.
template<int K, int N>
__global__ __launch_bounds__(256) void k_gemm(const float* __restrict__ A,
                                              const float* __restrict__ B,
                                              float* __restrict__ C,
                                              const float* __restrict__ dis, int M) {
    constexpr int BM = 64, BK = 32;
    constexpr int CPT = N / 16;
    __shared__ float sA[BK][BM + 4];
    __shared__ float sB[BK][N];

    const int tid  = threadIdx.x;
    const int row0 = blockIdx.x * BM;
    const int tr   = tid >> 4;
    const int tc   = tid & 15;

    float acc[4][CPT];
    #pragma unroll
    for (int i = 0; i < 4; ++i)
        #pragma unroll
        for (int j = 0; j < CPT; ++j) acc[i][j] = 0.f;

    for (int k0 = 0; k0 < K; k0 += BK) {
        #pragma unroll
        for (int l = 0; l < 2; ++l) {
            int t  = tid + l * 256;
            int r  = t >> 3;
            int cc = (t & 7) << 2;
            int gr = row0 + r;
            float4 v = make_float4(0.f, 0.f, 0.f, 0.f);
            if (gr < M) v = *(const float4*)(A + gr * K + k0 + cc);
            sA[cc + 0][r] = v.x; sA[cc + 1][r] = v.y;
            sA[cc + 2][r] = v.z; sA[cc + 3][r] = v.w;
        }
        #pragma unroll
        for (int l = 0; l < (8 * N) / 256; ++l) {
            int t  = tid + l * 256;
            int r  = t / (N / 4);
            int cc = (t % (N / 4)) << 2;
            *(float4*)(&sB[r][cc]) = *(const float4*)(B + (k0 + r) * N + cc);
        }
        __syncthreads();
        #pragma unroll
        for (int k = 0; k < BK; ++k) {
            float a[4], b[CPT];
            *(float4*)a = *(const float4*)(&sA[k][tr * 4]);
            #pragma unroll
            for (int j = 0; j < CPT; j += 4)
                *(float4*)(&b[j]) = *(const float4*)(&sB[k][tc * CPT + j]);
            #pragma unroll
            for (int i = 0; i < 4; ++i)
                #pragma unroll
                for (int j = 0; j < CPT; ++j)
                    acc[i][j] += a[i] * b[j];
        }
        __syncthreads();
    }
    #pragma unroll
    for (int i = 0; i < 4; ++i) {
        int row = row0 + tr * 4 + i;
        if (row < M) {
            float dn = dis[row];
            #pragma unroll
            for (int j = 0; j < CPT; ++j) acc[i][j] *= dn;
            #pragma unroll
            for (int j = 0; j < CPT; j += 4)
                *(float4*)(C + row * N + tc * CPT + j) = *(float4*)(&acc[i][j]);
        }
    }
}

// out[d,c] = relu?( (sum_{e in row d} feat[csr[e],c] + feat[d,c]) * dis[d] + bias[c] )
// feat is already pre-scaled by dis[src] (GEMM epilogue), so msg norm = dis[s]*dis[d].
template<int C, bool RELU>
__global__ __launch_bounds__(C) void k_agg(const int* __restrict__ rowptr,
                                           const int* __restrict__ csr,
                                           const float* __restrict__ feat,
                                           const float* __restrict__ dis,
                                           const float* __restrict__ bias,
                                           float* __restrict__ out) {
    const int d = blockIdx.x;
    const int c = threadIdx.x;
    const int beg = rowptr[d], end = rowptr[d + 1];
    float sum = feat[d * C + c];            // self-loop term (pre-scaled by dis[d])
    int e = beg;
    for (; e + 4 <= end; e += 4) {
        int s0 = csr[e], s1 = csr[e + 1], s2 = csr[e + 2], s3 = csr[e + 3];
        float f0 = feat[s0 * C + c], f1 = feat[s1 * C + c];
        float f2 = feat[s2 * C + c], f3 = feat[s3 * C + c];
        sum += (f0 + f1) + (f2 + f3);
    }
    for (; e < end; ++e) sum += feat[csr[e] * C + c];
    float r = sum * dis[d] + bias[c];
    if (RELU) r = fmaxf(r, 0.f);
    out[d * C + c] = r;
}

extern "C" void kernel_launch(void* const* d_in, const int* in_sizes, int n_in,
                              void* d_out, int out_size, void* d_ws, size_t ws_size,
                              hipStream_t stream) {
    const float* x  = (const float*)d_in[0];
    const int*   ei = (const int*)d_in[1];
    const float* W1 = (const float*)d_in[2];
    const float* b1 = (const float*)d_in[3];
    const float* W2 = (const float*)d_in[4];
    const float* b2 = (const float*)d_in[5];
    float* z = (float*)d_out;

    char* ws = (char*)d_ws;
    float* dis    = (float*)(ws + 0);             // 400 KB
    int*   cnt    = (int*)  (ws + 524288);        // also reused as cursor
    int*   rowptr = (int*)  (ws + 1048576);       // NN+1 ints
    int*   bsum   = (int*)  (ws + 1572864);       // 391 ints
    int*   csr    = (int*)  (ws + 2097152);       // 6.4 MB
    float* xw     = (float*)(ws + 8912896);       // 51.2 MB (reused as hw)
    float* h      = (float*)(ws + 60817408);      // 51.2 MB

    const int* src = ei;
    const int* dst = ei + NE;

    // ---- degree + norm + CSR build ----
    k_zero_i<<<(NN + 255) / 256, 256, 0, stream>>>(cnt, NN);
    k_hist<<<4096, 256, 0, stream>>>(dst, cnt, NE);
    k_dis<<<(NN + 255) / 256, 256, 0, stream>>>(cnt, dis, NN);
    k_scan1<<<NB_SCAN, SCAN_B, 0, stream>>>(cnt, rowptr + 1, bsum, NN);
    k_scan2<<<1, 512, 0, stream>>>(bsum, NB_SCAN);
    k_scan3<<<NB_SCAN, SCAN_B, 0, stream>>>(rowptr, bsum, cnt /*cursor*/, NN);
    k_scatter<<<4096, 256, 0, stream>>>(src, dst, cnt /*cursor*/, csr, NE);

    // ---- layer 1 ----
    k_gemm<C_IN, C_HID><<<(NN + 63) / 64, 256, 0, stream>>>(x, W1, xw, dis, NN);
    k_agg<C_HID, true><<<NN, C_HID, 0, stream>>>(rowptr, csr, xw, dis, b1, h);

    // ---- layer 2 ----
    float* hw = xw;
    k_gemm<C_HID, C_OUT><<<(NN + 63) / 64, 256, 0, stream>>>(h, W2, hw, dis, NN);
    k_agg<C_OUT, false><<<NN, C_OUT, 0, stream>>>(rowptr, csr, hw, dis, b2, z);
}

// Round 8
// 895.453 us; speedup vs baseline: 1.9737x; 1.1062x over previous
//
#include <hip/hip_runtime.h>
#include <hip/hip_bf16.h>

// GCN 2-layer: z = A_n(relu(A_n(x@W1)+b1)@W2)+b2, A_n = D^-1/2 (A+I) D^-1/2
// N=100000, E=1600000, IN=768, HID=128, OUT=64.
// R2..R7: CSR-by-dst built on device; gather-sum agg; fused epilogues.
// R8: GEMMs -> split-bf16 (hi/lo) MFMA, 3 passes: hi*hi + hi*lo + lo*hi.
//     Error ~1e-5 (<< fp32 path's 0.002 absmax). W split+transposed once/call;
//     x/h split during LDS staging. LDS stride 40 bf16 (80B) -> ~2-way banks.

static constexpr int NN    = 100000;
static constexpr int NE    = 1600000;
static constexpr int C_IN  = 768;
static constexpr int C_HID = 128;
static constexpr int C_OUT = 64;
static constexpr int SCAN_B = 256;
static constexpr int NB_SCAN = (NN + SCAN_B - 1) / SCAN_B;   // 391

typedef __attribute__((ext_vector_type(8))) short bf16x8;
typedef __attribute__((ext_vector_type(4))) float f32x4;

__device__ __forceinline__ unsigned short f2bf(float f) {
    unsigned int x = __float_as_uint(f);
    unsigned int r = (x + 0x7fffu + ((x >> 16) & 1u)) >> 16;   // RNE
    return (unsigned short)r;
}
__device__ __forceinline__ float bf2f(unsigned short u) {
    return __uint_as_float(((unsigned int)u) << 16);
}

// ---------------- CSR build (unchanged from R7) ----------------
__global__ void k_zero_i(int* __restrict__ p, int n) {
    int i = blockIdx.x * blockDim.x + threadIdx.x;
    if (i < n) p[i] = 0;
}

__global__ void k_hist(const int* __restrict__ dst, int* __restrict__ cnt, int e) {
    int stride = gridDim.x * blockDim.x;
    for (int i = blockIdx.x * blockDim.x + threadIdx.x; i < e; i += stride)
        atomicAdd(&cnt[dst[i]], 1);
}

__global__ void k_dis(const int* __restrict__ cnt, float* __restrict__ dis, int n) {
    int i = blockIdx.x * blockDim.x + threadIdx.x;
    if (i < n) dis[i] = rsqrtf((float)cnt[i] + 1.0f);
}

__global__ __launch_bounds__(SCAN_B) void k_scan1(const int* __restrict__ cnt,
                                                  int* __restrict__ rp1,
                                                  int* __restrict__ bsum, int n) {
    __shared__ int sh[SCAN_B];
    int b = blockIdx.x, t = threadIdx.x, i = b * SCAN_B + t;
    sh[t] = (i < n) ? cnt[i] : 0;
    __syncthreads();
    for (int off = 1; off < SCAN_B; off <<= 1) {
        int u = (t >= off) ? sh[t - off] : 0;
        __syncthreads();
        sh[t] += u;
        __syncthreads();
    }
    if (i < n) rp1[i] = sh[t];
    if (t == SCAN_B - 1) bsum[b] = sh[t];
}

__global__ __launch_bounds__(512) void k_scan2(int* __restrict__ bsum, int nb) {
    __shared__ int sh[512];
    int t = threadIdx.x;
    sh[t] = (t < nb) ? bsum[t] : 0;
    __syncthreads();
    for (int off = 1; off < 512; off <<= 1) {
        int u = (t >= off) ? sh[t - off] : 0;
        __syncthreads();
        sh[t] += u;
        __syncthreads();
    }
    if (t < nb) bsum[t] = sh[t];
}

__global__ __launch_bounds__(SCAN_B) void k_scan3(int* __restrict__ rowptr,
                                                  const int* __restrict__ bsum,
                                                  int* __restrict__ cursor, int n) {
    int b = blockIdx.x, t = threadIdx.x, i = b * SCAN_B + t;
    if (b == 0 && t == 0) { rowptr[0] = 0; cursor[0] = 0; }
    if (i < n) {
        int v = rowptr[1 + i] + (b > 0 ? bsum[b - 1] : 0);
        rowptr[1 + i] = v;
        if (i + 1 < n) cursor[i + 1] = v;
    }
}

__global__ void k_scatter(const int* __restrict__ src, const int* __restrict__ dst,
                          int* __restrict__ cursor, int* __restrict__ csr, int e) {
    int stride = gridDim.x * blockDim.x;
    for (int i = blockIdx.x * blockDim.x + threadIdx.x; i < e; i += stride) {
        int p = atomicAdd(&cursor[dst[i]], 1);
        csr[p] = src[i];
    }
}

// ---------------- weight split: W[K][N] -> Wt_hi/Wt_lo[N][K] (bf16) ----------
template<int K, int N>
__global__ void k_splitW(const float* __restrict__ W,
                         unsigned short* __restrict__ th,
                         unsigned short* __restrict__ tl) {
    int idx = blockIdx.x * blockDim.x + threadIdx.x;
    if (idx < K * N) {
        int k = idx / N, n = idx - k * N;
        float a = W[idx];
        unsigned short h = f2bf(a);
        th[n * K + k] = h;
        tl[n * K + k] = f2bf(a - bf2f(h));
    }
}

// ---------------- split-bf16 MFMA GEMM ----------------
// C[M,N_] = (A[M,K] @ B[K,N_]) * dis[row], A fp32, B pre-split bf16 [N_][K].
// Block: 256 thr (4 waves), tile 64 x N_. BK=32.
// N_=128: wave w -> cols [w*32,+32), rows 0..63  (4 row-tiles x 2 col-tiles)
// N_=64 : wave w -> rows [(w>>1)*32,+32), cols [(w&1)*32,+32)  (2x2 tiles)
template<int K, int N_>
__global__ __launch_bounds__(256) void k_gemm_mfma(const float* __restrict__ A,
                                                   const unsigned short* __restrict__ Bh,
                                                   const unsigned short* __restrict__ Bl,
                                                   float* __restrict__ C,
                                                   const float* __restrict__ dis, int M) {
    constexpr int RT = (N_ == 128) ? 4 : 2;
    constexpr int CT = 2;
    constexpr int LDK = 40;                       // padded k-stride (80 B)

    __shared__ unsigned short sAh[64][LDK], sAl[64][LDK];
    __shared__ unsigned short sBh[N_][LDK], sBl[N_][LDK];

    const int tid  = threadIdx.x;
    const int w    = tid >> 6;
    const int lane = tid & 63;
    const int lr   = lane & 15;                   // row(A)/col(B)/col(D) in tile
    const int ls   = lane >> 4;                   // k-segment; D-row group
    const int row0 = blockIdx.x * 64;

    const int row_base = (N_ == 128) ? 0 : (w >> 1) * 32;
    const int col_base = (N_ == 128) ? w * 32 : (w & 1) * 32;

    f32x4 acc[RT][CT];
    #pragma unroll
    for (int i = 0; i < RT; ++i)
        #pragma unroll
        for (int j = 0; j < CT; ++j) acc[i][j] = (f32x4){0.f, 0.f, 0.f, 0.f};

    for (int k0 = 0; k0 < K; k0 += 32) {
        // ---- stage A: 64 rows x 32 k fp32 -> hi/lo bf16 ----
        #pragma unroll
        for (int l = 0; l < 2; ++l) {
            int f   = tid + l * 256;              // 0..511 float4 chunks
            int row = f >> 3;
            int kc  = (f & 7) << 2;
            int gr  = row0 + row;
            float4 v = make_float4(0.f, 0.f, 0.f, 0.f);
            if (gr < M) v = *(const float4*)(A + gr * K + k0 + kc);
            unsigned short h0 = f2bf(v.x), h1 = f2bf(v.y), h2 = f2bf(v.z), h3 = f2bf(v.w);
            *(short4*)&sAh[row][kc] = make_short4(h0, h1, h2, h3);
            *(short4*)&sAl[row][kc] = make_short4(f2bf(v.x - bf2f(h0)), f2bf(v.y - bf2f(h1)),
                                                  f2bf(v.z - bf2f(h2)), f2bf(v.w - bf2f(h3)));
        }
        // ---- stage B: N_ cols x 32 k bf16 (hi & lo), contiguous 16B chunks ----
        #pragma unroll
        for (int l = 0; l < (N_ * 4) / 256; ++l) {
            int c   = tid + l * 256;
            int col = c >> 2;
            int kc8 = (c & 3) * 8;
            *(uint4*)&sBh[col][kc8] = *(const uint4*)&Bh[col * K + k0 + kc8];
            *(uint4*)&sBl[col][kc8] = *(const uint4*)&Bl[col * K + k0 + kc8];
        }
        __syncthreads();

        // ---- fragments: lane holds 8 contiguous k at k=ls*8 ----
        bf16x8 ah[RT], al[RT], bh[CT], bl[CT];
        #pragma unroll
        for (int rt = 0; rt < RT; ++rt) {
            int arow = row_base + rt * 16 + lr;
            ah[rt] = *(const bf16x8*)&sAh[arow][ls * 8];
            al[rt] = *(const bf16x8*)&sAl[arow][ls * 8];
        }
        #pragma unroll
        for (int ct = 0; ct < CT; ++ct) {
            int bcol = col_base + ct * 16 + lr;
            bh[ct] = *(const bf16x8*)&sBh[bcol][ls * 8];
            bl[ct] = *(const bf16x8*)&sBl[bcol][ls * 8];
        }
        #pragma unroll
        for (int rt = 0; rt < RT; ++rt)
            #pragma unroll
            for (int ct = 0; ct < CT; ++ct) {
                acc[rt][ct] = __builtin_amdgcn_mfma_f32_16x16x32_bf16(ah[rt], bh[ct], acc[rt][ct], 0, 0, 0);
                acc[rt][ct] = __builtin_amdgcn_mfma_f32_16x16x32_bf16(ah[rt], bl[ct], acc[rt][ct], 0, 0, 0);
                acc[rt][ct] = __builtin_amdgcn_mfma_f32_16x16x32_bf16(al[rt], bh[ct], acc[rt][ct], 0, 0, 0);
            }
        __syncthreads();
    }

    // ---- epilogue: D[row=ls*4+r][col=lr] per tile; scale by dis ----
    #pragma unroll
    for (int rt = 0; rt < RT; ++rt) {
        #pragma unroll
        for (int r = 0; r < 4; ++r) {
            int grow = row0 + row_base + rt * 16 + ls * 4 + r;
            if (grow < M) {
                float dn = dis[grow];
                #pragma unroll
                for (int ct = 0; ct < CT; ++ct) {
                    int gcol = col_base + ct * 16 + lr;
                    C[grow * N_ + gcol] = acc[rt][ct][r] * dn;
                }
            }
        }
    }
}

// ---------------- aggregation (unchanged from R7) ----------------
template<int C, bool RELU>
__global__ __launch_bounds__(C) void k_agg(const int* __restrict__ rowptr,
                                           const int* __restrict__ csr,
                                           const float* __restrict__ feat,
                                           const float* __restrict__ dis,
                                           const float* __restrict__ bias,
                                           float* __restrict__ out) {
    const int d = blockIdx.x;
    const int c = threadIdx.x;
    const int beg = rowptr[d], end = rowptr[d + 1];
    float sum = feat[d * C + c];
    int e = beg;
    for (; e + 4 <= end; e += 4) {
        int s0 = csr[e], s1 = csr[e + 1], s2 = csr[e + 2], s3 = csr[e + 3];
        float f0 = feat[s0 * C + c], f1 = feat[s1 * C + c];
        float f2 = feat[s2 * C + c], f3 = feat[s3 * C + c];
        sum += (f0 + f1) + (f2 + f3);
    }
    for (; e < end; ++e) sum += feat[csr[e] * C + c];
    float r = sum * dis[d] + bias[c];
    if (RELU) r = fmaxf(r, 0.f);
    out[d * C + c] = r;
}

extern "C" void kernel_launch(void* const* d_in, const int* in_sizes, int n_in,
                              void* d_out, int out_size, void* d_ws, size_t ws_size,
                              hipStream_t stream) {
    const float* x  = (const float*)d_in[0];
    const int*   ei = (const int*)d_in[1];
    const float* W1 = (const float*)d_in[2];
    const float* b1 = (const float*)d_in[3];
    const float* W2 = (const float*)d_in[4];
    const float* b2 = (const float*)d_in[5];
    float* z = (float*)d_out;

    char* ws = (char*)d_ws;
    float* dis    = (float*)(ws + 0);                  // 400 KB
    int*   cnt    = (int*)  (ws + 524288);             // reused as cursor
    int*   rowptr = (int*)  (ws + 1048576);            // NN+1
    int*   bsum   = (int*)  (ws + 1572864);            // 391
    int*   csr    = (int*)  (ws + 2097152);            // 6.4 MB
    unsigned short* w1h = (unsigned short*)(ws + 8912896);   // 128x768 bf16 = 192 KB
    unsigned short* w1l = (unsigned short*)(ws + 9109504);
    unsigned short* w2h = (unsigned short*)(ws + 9306112);   // 64x128 bf16 = 16 KB
    unsigned short* w2l = (unsigned short*)(ws + 9322496);
    float* xw     = (float*)(ws + 9437184);            // 51.2 MB (reused as hw)
    float* h      = (float*)(ws + 60817408);           // 51.2 MB

    const int* src = ei;
    const int* dst = ei + NE;

    // ---- degree + norm + CSR build ----
    k_zero_i<<<(NN + 255) / 256, 256, 0, stream>>>(cnt, NN);
    k_hist<<<4096, 256, 0, stream>>>(dst, cnt, NE);
    k_dis<<<(NN + 255) / 256, 256, 0, stream>>>(cnt, dis, NN);
    k_scan1<<<NB_SCAN, SCAN_B, 0, stream>>>(cnt, rowptr + 1, bsum, NN);
    k_scan2<<<1, 512, 0, stream>>>(bsum, NB_SCAN);
    k_scan3<<<NB_SCAN, SCAN_B, 0, stream>>>(rowptr, bsum, cnt /*cursor*/, NN);
    k_scatter<<<4096, 256, 0, stream>>>(src, dst, cnt /*cursor*/, csr, NE);

    // ---- weight split (bf16 hi/lo, transposed) ----
    k_splitW<C_IN, C_HID><<<(C_IN * C_HID + 255) / 256, 256, 0, stream>>>(W1, w1h, w1l);
    k_splitW<C_HID, C_OUT><<<(C_HID * C_OUT + 255) / 256, 256, 0, stream>>>(W2, w2h, w2l);

    // ---- layer 1 ----
    k_gemm_mfma<C_IN, C_HID><<<(NN + 63) / 64, 256, 0, stream>>>(x, w1h, w1l, xw, dis, NN);
    k_agg<C_HID, true><<<NN, C_HID, 0, stream>>>(rowptr, csr, xw, dis, b1, h);

    // ---- layer 2 ----
    float* hw = xw;
    k_gemm_mfma<C_HID, C_OUT><<<(NN + 63) / 64, 256, 0, stream>>>(h, w2h, w2l, hw, dis, NN);
    k_agg<C_OUT, false><<<NN, C_OUT, 0, stream>>>(rowptr, csr, hw, dis, b2, z);
}